// Round 2
// baseline (208.409 us; speedup 1.0000x reference)
//
#include <hip/hip_runtime.h>

// Gray-Scott PDE residual, 4-way T-split t-march, float4/thread,
// nontemporal output stores, XCD-pinned batches.
//   in  : (T=20, B=8, C=3, H=256, W=256) fp32; u = ch1, v = ch2
//   out : [f_u | f_v], each (20,8,1,252,252) fp32
//
// R2 vs R1: same 4-chunk T-split grid (2016 blocks, 7.9 blocks/CU of work,
// 4 resident via launch_bounds(256,4)), but each chunk now dispatches to a
// template march with COMPILE-TIME loop bounds -> full unroll restored
// (R1's runtime ts/te killed cross-iteration load pipelining), and
// per-chunk register trimming: l0 regs only live in chunk 0, cm2 regs only
// in chunk 3 (R1 kept all live under a 128-VGPR cap -> spill risk).
// Evidence: R1 cost exactly its +25 MB traffic at 3 TB/s -> occupancy gave
// zero latency win because per-wave ILP regressed. This isolates that.

#define T_OUT (8 * 252 * 252)

typedef float vf4 __attribute__((ext_vector_type(4)));

static __device__ __forceinline__ vf4 ldu4(const float* p) {
    vf4 v;
    __builtin_memcpy(&v, p, 16);   // 8B-aligned 16B load; gfx950 handles it
    return v;
}

#define GS_INT(c) { \
    float ut = (ucn.c - u_cm1.c) * hdt; \
    float vt = (vcn.c - v_cm1.c) * hdt; \
    float uvv = u_cc.c * v_cc.c * v_cc.c; \
    fu.c = Du * u_lm1.c - uvv + fR * (1.0f - u_cc.c) - ut; \
    fv.c = Dv * v_lm1.c + uvv - (fR + kR) * v_cc.c - vt; }

#define GS_T0(c) { \
    float ut = (-1.5f * u_cm1.c + 2.0f * u_cc.c - 0.5f * ucn.c) * inv_dt; \
    float vt = (-1.5f * v_cm1.c + 2.0f * v_cc.c - 0.5f * vcn.c) * inv_dt; \
    float uvv = u_cm1.c * v_cm1.c * v_cm1.c; \
    fu.c = Du * u_l0.c - uvv + fR * (1.0f - u_cm1.c) - ut; \
    fv.c = Dv * v_l0.c + uvv - (fR + kR) * v_cm1.c - vt; }

#define GS_TN(c) { \
    float ut = (0.5f * u_cm2.c - 2.0f * u_cm1.c + 1.5f * u_cc.c) * inv_dt; \
    float vt = (0.5f * v_cm2.c - 2.0f * v_cm1.c + 1.5f * v_cc.c) * inv_dt; \
    float uvv = u_cc.c * v_cc.c * v_cc.c; \
    fu.c = Du * u_lm1.c - uvv + fR * (1.0f - u_cc.c) - ut; \
    fv.c = Dv * v_lm1.c + uvv - (fR + kR) * v_cc.c - vt; }

// One t-chunk march with compile-time bounds. Emits outputs TS+1..TE-1
// (interior), plus output 0 (one-sided, FIRST) and output 19 (one-sided,
// LAST). Planes read: t = TS..TE.
template<int TS, int TE, bool FIRST, bool LAST>
static __device__ __forceinline__ void march(
    const float* __restrict__ ubase, float* __restrict__ outu,
    float* __restrict__ outv)
{
    const int planeStride = 256 * 256;
    const int tStride     = 24 * planeStride;

    const float C1 = 4.0f / 3.0f, C2 = 1.0f / 12.0f;
    const float inv_dx2 = 1.0f / (0.15625f * 0.15625f);   // DX = 20/128
    const float inv_dt  = 20.0f;                          // 1/DT
    const float hdt     = 10.0f;                          // 1/(2 DT)
    const float Du = 0.16f, Dv = 0.08f, fR = 0.06f, kR = 0.062f;

    vf4 u_cm2{}, u_cm1{}, u_cc{}, u_lm1{}, u_l0{};
    vf4 v_cm2{}, v_cm1{}, v_cc{}, v_lm1{}, v_l0{};

#pragma unroll
    for (int t = TS; t <= TE; ++t) {
        const float* up = ubase + (size_t)t * tStride;
        const float* vp = up + planeStride;

        // center row: cols x0..x0+7 as two aligned 16B loads
        vf4 uL = *(const vf4*)(up);
        vf4 uR = *(const vf4*)(up + 4);
        // halo rows: cols x0+2..x0+5 as one (8B-aligned) 16B load each
        vf4 um1 = ldu4(up - 256 + 2);
        vf4 up1 = ldu4(up + 256 + 2);
        vf4 um2 = ldu4(up - 512 + 2);
        vf4 up2 = ldu4(up + 512 + 2);

        vf4 vL = *(const vf4*)(vp);
        vf4 vR = *(const vf4*)(vp + 4);
        vf4 vm1 = ldu4(vp - 256 + 2);
        vf4 vp1 = ldu4(vp + 256 + 2);
        vf4 vm2 = ldu4(vp - 512 + 2);
        vf4 vp2 = ldu4(vp + 512 + 2);

        vf4 lu, lv;
        lu.x = (C1*(uL.y + uL.w + um1.x + up1.x) - C2*(uL.x + uR.x + um2.x + up2.x) - 5.0f*uL.z) * inv_dx2;
        lu.y = (C1*(uL.z + uR.x + um1.y + up1.y) - C2*(uL.y + uR.y + um2.y + up2.y) - 5.0f*uL.w) * inv_dx2;
        lu.z = (C1*(uL.w + uR.y + um1.z + up1.z) - C2*(uL.z + uR.z + um2.z + up2.z) - 5.0f*uR.x) * inv_dx2;
        lu.w = (C1*(uR.x + uR.z + um1.w + up1.w) - C2*(uL.w + uR.w + um2.w + up2.w) - 5.0f*uR.y) * inv_dx2;
        lv.x = (C1*(vL.y + vL.w + vm1.x + vp1.x) - C2*(vL.x + vR.x + vm2.x + vp2.x) - 5.0f*vL.z) * inv_dx2;
        lv.y = (C1*(vL.z + vR.x + vm1.y + vp1.y) - C2*(vL.y + vR.y + vm2.y + vp2.y) - 5.0f*vL.w) * inv_dx2;
        lv.z = (C1*(vL.w + vR.y + vm1.z + vp1.z) - C2*(vL.z + vR.z + vm2.z + vp2.z) - 5.0f*vR.x) * inv_dx2;
        lv.w = (C1*(vR.x + vR.z + vm1.w + vp1.w) - C2*(vL.w + vR.w + vm2.w + vp2.w) - 5.0f*vR.y) * inv_dx2;

        vf4 ucn = {uL.z, uL.w, uR.x, uR.y};   // centers at t
        vf4 vcn = {vL.z, vL.w, vR.x, vR.y};

        if (FIRST && t == TS) { u_l0 = lu; v_l0 = lv; }

        if (FIRST && t == TS + 2) {
            // emit t=0 one-sided: c0=cm1, c1=cc, c2=ucn, lap=l0
            vf4 fu, fv;
            GS_T0(x); GS_T0(y); GS_T0(z); GS_T0(w);
            __builtin_nontemporal_store(fu, (vf4*)(outu));
            __builtin_nontemporal_store(fv, (vf4*)(outv));
        }

        if (t >= TS + 2) {
            // emit t-1 interior: center=cc, u_t=(c_t - c_{t-2})/(2DT), lap=lm1
            vf4 fu, fv;
            GS_INT(x); GS_INT(y); GS_INT(z); GS_INT(w);
            __builtin_nontemporal_store(fu, (vf4*)(outu + (size_t)(t - 1) * T_OUT));
            __builtin_nontemporal_store(fv, (vf4*)(outv + (size_t)(t - 1) * T_OUT));
        }

        if (LAST) { u_cm2 = u_cm1; v_cm2 = v_cm1; }
        u_cm1 = u_cc; u_cc = ucn; u_lm1 = lu;
        v_cm1 = v_cc; v_cc = vcn; v_lm1 = lv;
    }

    if (LAST) {
        // emit t=19 one-sided: c17=cm2, c18=cm1, c19=cc, lap19=lm1
        vf4 fu, fv;
        GS_TN(x); GS_TN(y); GS_TN(z); GS_TN(w);
        __builtin_nontemporal_store(fu, (vf4*)(outu + (size_t)19 * T_OUT));
        __builtin_nontemporal_store(fv, (vf4*)(outv + (size_t)19 * T_OUT));
    }
}

__global__ __launch_bounds__(256, 4) void gs_loss_kernel(
    const float* __restrict__ in, float* __restrict__ out)
{
    const int tid  = threadIdx.x;
    const int xg   = tid & 63;          // 63 active x-groups of 4
    const int yloc = tid >> 6;          // 0..3
    if (xg >= 63) return;

    const int b     = blockIdx.x & 7;   // batch -> XCD pinning
    const int rest  = blockIdx.x >> 3;  // 0..251
    const int chunk = rest & 3;         // t-chunk (low bits: all chunks live
                                        // from dispatch 0)
    const int ytile = rest >> 2;        // 0..62

    const int y  = ytile * 4 + yloc;    // 0..251
    const int x0 = xg * 4;              // 16B-aligned plane column

    const int planeStride = 256 * 256;
    const int bStride     = 3 * planeStride;

    // u-plane (ch1) address of row y+2, col x0 (centers at cols x0+2..x0+5)
    const float* ubase = in + (size_t)b * bStride + planeStride
                         + (size_t)(y + 2) * 256 + x0;

    const int total = 20 * T_OUT;
    float* outu = out + ((size_t)b * 252 + y) * 252 + x0;
    float* outv = outu + total;

    // chunk c emits outputs [5c, 5c+5); marches planes 5c-1..5c+5
    // (one-sided at the ends). Compile-time bounds -> full unroll.
    switch (chunk) {
        case 0:  march< 0,  5, true,  false>(ubase, outu, outv); break;
        case 1:  march< 4, 10, false, false>(ubase, outu, outv); break;
        case 2:  march< 9, 15, false, false>(ubase, outu, outv); break;
        default: march<14, 19, false, true >(ubase, outu, outv); break;
    }
}

extern "C" void kernel_launch(void* const* d_in, const int* in_sizes, int n_in,
                              void* d_out, int out_size, void* d_ws, size_t ws_size,
                              hipStream_t stream) {
    const float* in = (const float*)d_in[0];
    float* out = (float*)d_out;

    // 4 t-chunks * 63 y-tiles * 8 b = 2016 blocks of 256 threads
    gs_loss_kernel<<<4 * 8 * 63, 256, 0, stream>>>(in, out);
}

// Round 5
// 191.023 us; speedup vs baseline: 1.0910x; 1.0910x over previous
//
#include <hip/hip_runtime.h>

// Gray-Scott PDE residual, single full t-march + LDS-staged stencil tiles.
//   in  : (T=20, B=8, C=3, H=256, W=256) fp32; u = ch1, v = ch2
//   out : [f_u | f_v], each (20,8,1,252,252) fp32
//
// R5 == R3/R4 resubmitted (GPUAcquisitionTimeout, then container failure;
// never measured). Rationale: R1/R2 proved the kernel is NOT latency-bound
// (2x waves, full unroll -> no gain) and that cost scales with LOAD-PATH
// bytes at ~3 TB/s even for L3-resident re-reads. R0 pushed 634 MB of 16B
// vector loads (one-third 8B-misaligned) through VMEM/L1/L2. This version
// stages each block's 16 input rows (8 u + 8 v, 16 KB) into LDS per t with
// four aligned fully-coalesced dwordx4 loads/thread (64 B/thread/t, 161 MB
// total), double-buffered (32 KB) with ONE barrier per t; t+1 loads are
// issued before the compute phase so HBM latency hides under the VALU
// work (T14 async-stage split). Stencil reads come from LDS (bank-
// conflict-free: 64 lanes x 16B consecutive).

#define T_OUT (8 * 252 * 252)

typedef float vf4 __attribute__((ext_vector_type(4)));

static __device__ __forceinline__ vf4 lds4u(const float* p) {
    vf4 v;
    __builtin_memcpy(&v, p, 16);   // 8B-aligned LDS 16B read -> ds_read2_b64
    return v;
}

#define GS_INT(c) { \
    float ut = (ucn.c - u_cm1.c) * hdt; \
    float vt = (vcn.c - v_cm1.c) * hdt; \
    float uvv = u_cc.c * v_cc.c * v_cc.c; \
    fu.c = Du * u_lm1.c - uvv + fR * (1.0f - u_cc.c) - ut; \
    fv.c = Dv * v_lm1.c + uvv - (fR + kR) * v_cc.c - vt; }

#define GS_T0(c) { \
    float ut = (-1.5f * u_cm1.c + 2.0f * u_cc.c - 0.5f * ucn.c) * inv_dt; \
    float vt = (-1.5f * v_cm1.c + 2.0f * v_cc.c - 0.5f * vcn.c) * inv_dt; \
    float uvv = u_cm1.c * v_cm1.c * v_cm1.c; \
    fu.c = Du * u_l0.c - uvv + fR * (1.0f - u_cm1.c) - ut; \
    fv.c = Dv * v_l0.c + uvv - (fR + kR) * v_cm1.c - vt; }

#define GS_TN(c) { \
    float ut = (0.5f * u_cm2.c - 2.0f * u_cm1.c + 1.5f * u_cc.c) * inv_dt; \
    float vt = (0.5f * v_cm2.c - 2.0f * v_cm1.c + 1.5f * v_cc.c) * inv_dt; \
    float uvv = u_cc.c * v_cc.c * v_cc.c; \
    fu.c = Du * u_lm1.c - uvv + fR * (1.0f - u_cc.c) - ut; \
    fv.c = Dv * v_lm1.c + uvv - (fR + kR) * v_cc.c - vt; }

// Issue the 4 staging loads for plane-set t into sreg0..3.
// k=0: u row y0+w, k=1: u row y0+w+4, k=2: v row y0+w, k=3: v row y0+w+4.
#define ISSUE(t) { \
    const float* bt = base0 + (size_t)(t) * tStride; \
    sreg0 = *(const vf4*)(bt + (size_t)(y0 + w) * 256 + col); \
    sreg1 = *(const vf4*)(bt + (size_t)(y0 + w + 4) * 256 + col); \
    sreg2 = *(const vf4*)(bt + planeStride + (size_t)(y0 + w) * 256 + col); \
    sreg3 = *(const vf4*)(bt + planeStride + (size_t)(y0 + w + 4) * 256 + col); }

__global__ __launch_bounds__(256) void gs_loss_kernel(
    const float* __restrict__ in, float* __restrict__ out)
{
    // [buf][row][col]: rows 0..7 = u plane rows y0..y0+7, rows 8..15 = v.
    __shared__ float lds[2][16][256];

    const int tid = threadIdx.x;
    const int w   = tid >> 6;           // wave id = yloc (0..3)
    const int ln  = tid & 63;           // lane    = xg  (0..63)

    const int b     = blockIdx.x & 7;   // batch -> XCD pinning
    const int ytile = blockIdx.x >> 3;  // 0..62
    const int y0    = ytile * 4;

    const int planeStride = 256 * 256;
    const int bStride     = 3 * planeStride;
    const int tStride     = 24 * planeStride;

    const int col = ln * 4;             // staging column (16B aligned)
    const float* base0 = in + (size_t)b * bStride + planeStride;  // u, t=0

    // compute-role coords: thread owns 4 x-outputs of row y = y0 + w
    const int yloc = w;
    const int xg   = ln;
    const int x0   = xg * 4;
    const bool active = (xg < 63);      // 252 of 256 x-positions

    const int total = 20 * T_OUT;
    float* outu = out + ((size_t)b * 252 + (y0 + yloc)) * 252 + x0;
    float* outv = outu + total;

    const float C1 = 4.0f / 3.0f, C2 = 1.0f / 12.0f;
    const float inv_dx2 = 1.0f / (0.15625f * 0.15625f);   // DX = 20/128
    const float inv_dt  = 20.0f;                          // 1/DT
    const float hdt     = 10.0f;                          // 1/(2 DT)
    const float Du = 0.16f, Dv = 0.08f, fR = 0.06f, kR = 0.062f;

    vf4 u_cm2{}, u_cm1{}, u_cc{}, u_lm1{}, u_l0{};
    vf4 v_cm2{}, v_cm1{}, v_cc{}, v_lm1{}, v_l0{};

    vf4 sreg0, sreg1, sreg2, sreg3;
    ISSUE(0);

#pragma unroll
    for (int t = 0; t < 20; ++t) {
        float (*L)[256] = lds[t & 1];

        // stage t (compiler inserts the vmcnt for sreg arrival)
        *(vf4*)&L[w     ][col] = sreg0;
        *(vf4*)&L[w + 4 ][col] = sreg1;
        *(vf4*)&L[w + 8 ][col] = sreg2;
        *(vf4*)&L[w + 12][col] = sreg3;

        __syncthreads();
        // Single barrier per t is safe with the double buffer: a wave
        // writing lds[(t+2)&1] has passed barrier(t+1), which implies all
        // waves finished compute(t) (reads of that same buffer).

        // prefetch t+1 while this t computes (hides HBM latency)
        if (t < 19) ISSUE(t + 1);

        if (active) {
            // u stencil rows (LDS rows yloc..yloc+4), v at +8
            vf4 uL  = *(const vf4*)&L[yloc + 2][x0];
            vf4 uR  = *(const vf4*)&L[yloc + 2][x0 + 4];
            vf4 um1 = lds4u(&L[yloc + 1][x0 + 2]);
            vf4 up1 = lds4u(&L[yloc + 3][x0 + 2]);
            vf4 um2 = lds4u(&L[yloc    ][x0 + 2]);
            vf4 up2 = lds4u(&L[yloc + 4][x0 + 2]);

            vf4 vL  = *(const vf4*)&L[yloc + 10][x0];
            vf4 vR  = *(const vf4*)&L[yloc + 10][x0 + 4];
            vf4 vm1 = lds4u(&L[yloc +  9][x0 + 2]);
            vf4 vp1 = lds4u(&L[yloc + 11][x0 + 2]);
            vf4 vm2 = lds4u(&L[yloc +  8][x0 + 2]);
            vf4 vp2 = lds4u(&L[yloc + 12][x0 + 2]);

            vf4 lu, lv;
            lu.x = (C1*(uL.y + uL.w + um1.x + up1.x) - C2*(uL.x + uR.x + um2.x + up2.x) - 5.0f*uL.z) * inv_dx2;
            lu.y = (C1*(uL.z + uR.x + um1.y + up1.y) - C2*(uL.y + uR.y + um2.y + up2.y) - 5.0f*uL.w) * inv_dx2;
            lu.z = (C1*(uL.w + uR.y + um1.z + up1.z) - C2*(uL.z + uR.z + um2.z + up2.z) - 5.0f*uR.x) * inv_dx2;
            lu.w = (C1*(uR.x + uR.z + um1.w + up1.w) - C2*(uL.w + uR.w + um2.w + up2.w) - 5.0f*uR.y) * inv_dx2;
            lv.x = (C1*(vL.y + vL.w + vm1.x + vp1.x) - C2*(vL.x + vR.x + vm2.x + vp2.x) - 5.0f*vL.z) * inv_dx2;
            lv.y = (C1*(vL.z + vR.x + vm1.y + vp1.y) - C2*(vL.y + vR.y + vm2.y + vp2.y) - 5.0f*vL.w) * inv_dx2;
            lv.z = (C1*(vL.w + vR.y + vm1.z + vp1.z) - C2*(vL.z + vR.z + vm2.z + vp2.z) - 5.0f*vR.x) * inv_dx2;
            lv.w = (C1*(vR.x + vR.z + vm1.w + vp1.w) - C2*(vL.w + vR.w + vm2.w + vp2.w) - 5.0f*vR.y) * inv_dx2;

            vf4 ucn = {uL.z, uL.w, uR.x, uR.y};   // centers at t
            vf4 vcn = {vL.z, vL.w, vR.x, vR.y};

            if (t == 0) { u_l0 = lu; v_l0 = lv; }

            if (t == 2) {
                // emit t=0 one-sided: c0=cm1, c1=cc, c2=ucn, lap=l0
                vf4 fu, fv;
                GS_T0(x); GS_T0(y); GS_T0(z); GS_T0(w);
                __builtin_nontemporal_store(fu, (vf4*)(outu));
                __builtin_nontemporal_store(fv, (vf4*)(outv));
            }

            if (t >= 2) {
                // emit t-1 interior: center=cc, u_t=(c_t - c_{t-2})/(2DT)
                vf4 fu, fv;
                GS_INT(x); GS_INT(y); GS_INT(z); GS_INT(w);
                __builtin_nontemporal_store(fu, (vf4*)(outu + (size_t)(t - 1) * T_OUT));
                __builtin_nontemporal_store(fv, (vf4*)(outv + (size_t)(t - 1) * T_OUT));
            }

            u_cm2 = u_cm1; u_cm1 = u_cc; u_cc = ucn; u_lm1 = lu;
            v_cm2 = v_cm1; v_cm1 = v_cc; v_cc = vcn; v_lm1 = lv;
        }
    }

    if (active) {
        // emit t=19 one-sided: c17=cm2, c18=cm1, c19=cc, lap19=lm1
        vf4 fu, fv;
        GS_TN(x); GS_TN(y); GS_TN(z); GS_TN(w);
        __builtin_nontemporal_store(fu, (vf4*)(outu + (size_t)19 * T_OUT));
        __builtin_nontemporal_store(fv, (vf4*)(outv + (size_t)19 * T_OUT));
    }
}

extern "C" void kernel_launch(void* const* d_in, const int* in_sizes, int n_in,
                              void* d_out, int out_size, void* d_ws, size_t ws_size,
                              hipStream_t stream) {
    const float* in = (const float*)d_in[0];
    float* out = (float*)d_out;

    // 8 b * 63 y-tiles = 504 blocks of 256 threads (~2 blocks/CU, 32KB LDS)
    gs_loss_kernel<<<8 * 63, 256, 0, stream>>>(in, out);
}

// Round 6
// 189.518 us; speedup vs baseline: 1.0997x; 1.0079x over previous
//
#include <hip/hip_runtime.h>

// Gray-Scott PDE residual, 8-row y-tiles, LDS-staged stencil, dist-2 prefetch.
//   in  : (T=20, B=8, C=3, H=256, W=256) fp32; u = ch1, v = ch2
//   out : [f_u | f_v], each (20,8,1,252,252) fp32
//
// R6 vs R5: R5 measured ~41 us kernel == 242 MB HBM / 5.9 TB/s (94% of
// achievable) -> HBM-traffic-bound; halo re-reads are NOT L2-absorbed.
// Lever = read amplification. R5: 4-row tiles read 8 rows/plane per 4
// outputs (2.0x amp). R6: 8-row tiles read 12 rows/plane per 8 outputs
// (1.48x incl. ragged tile) -> reads 161 -> 124 MB, total 242 -> 206 MB.
// Grid 32 ytiles x 8 b = 256 blocks (exactly 1/CU, no imbalance tail),
// 2 outputs/thread, 48 KB LDS dbuf, ONE barrier per t. 1 block/CU removes
// inter-block latency hiding, so prefetch depth is raised to 2 iterations
// (sregA/sregB ping-pong: ~1400 cy of compute cover vs ~900 cy HBM lat).

#define T_OUT (8 * 252 * 252)

typedef float vf4 __attribute__((ext_vector_type(4)));

static __device__ __forceinline__ vf4 lds4u(const float* p) {
    vf4 v;
    __builtin_memcpy(&v, p, 16);   // 8B-aligned LDS 16B read
    return v;
}

struct GSRow {
    vf4 u_cm2, u_cm1, u_cc, u_lm1, u_l0;
    vf4 v_cm2, v_cm1, v_cc, v_lm1, v_l0;
};

#define GS_INT(c) { \
    float ut = (ucn.c - s.u_cm1.c) * hdt; \
    float vt = (vcn.c - s.v_cm1.c) * hdt; \
    float uvv = s.u_cc.c * s.v_cc.c * s.v_cc.c; \
    fu.c = Du * s.u_lm1.c - uvv + fR * (1.0f - s.u_cc.c) - ut; \
    fv.c = Dv * s.v_lm1.c + uvv - (fR + kR) * s.v_cc.c - vt; }

#define GS_T0(c) { \
    float ut = (-1.5f * s.u_cm1.c + 2.0f * s.u_cc.c - 0.5f * ucn.c) * inv_dt; \
    float vt = (-1.5f * s.v_cm1.c + 2.0f * s.v_cc.c - 0.5f * vcn.c) * inv_dt; \
    float uvv = s.u_cm1.c * s.v_cm1.c * s.v_cm1.c; \
    fu.c = Du * s.u_l0.c - uvv + fR * (1.0f - s.u_cm1.c) - ut; \
    fv.c = Dv * s.v_l0.c + uvv - (fR + kR) * s.v_cm1.c - vt; }

#define GS_TN(c) { \
    float ut = (0.5f * s.u_cm2.c - 2.0f * s.u_cm1.c + 1.5f * s.u_cc.c) * inv_dt; \
    float vt = (0.5f * s.v_cm2.c - 2.0f * s.v_cm1.c + 1.5f * s.v_cc.c) * inv_dt; \
    float uvv = s.u_cc.c * s.v_cc.c * s.v_cc.c; \
    fu.c = Du * s.u_lm1.c - uvv + fR * (1.0f - s.u_cc.c) - ut; \
    fv.c = Dv * s.v_lm1.c + uvv - (fR + kR) * s.v_cc.c - vt; }

// One output row's GS update at time t. L rows: u = 0..11, v = 12..23.
// Output row uses LDS u rows R..R+4 (center R+2), v rows R+12..R+16.
static __device__ __forceinline__ void gs_step(
    const float (*L)[256], int R, int x0, int t, GSRow& s, bool act,
    float* __restrict__ outu, float* __restrict__ outv)
{
    const float C1 = 4.0f / 3.0f, C2 = 1.0f / 12.0f;
    const float inv_dx2 = 1.0f / (0.15625f * 0.15625f);   // DX = 20/128
    const float inv_dt  = 20.0f;                          // 1/DT
    const float hdt     = 10.0f;                          // 1/(2 DT)
    const float Du = 0.16f, Dv = 0.08f, fR = 0.06f, kR = 0.062f;

    vf4 uL  = *(const vf4*)&L[R + 2][x0];
    vf4 uR  = *(const vf4*)&L[R + 2][x0 + 4];
    vf4 um1 = lds4u(&L[R + 1][x0 + 2]);
    vf4 up1 = lds4u(&L[R + 3][x0 + 2]);
    vf4 um2 = lds4u(&L[R    ][x0 + 2]);
    vf4 up2 = lds4u(&L[R + 4][x0 + 2]);

    vf4 vL  = *(const vf4*)&L[R + 14][x0];
    vf4 vR  = *(const vf4*)&L[R + 14][x0 + 4];
    vf4 vm1 = lds4u(&L[R + 13][x0 + 2]);
    vf4 vp1 = lds4u(&L[R + 15][x0 + 2]);
    vf4 vm2 = lds4u(&L[R + 12][x0 + 2]);
    vf4 vp2 = lds4u(&L[R + 16][x0 + 2]);

    vf4 lu, lv;
    lu.x = (C1*(uL.y + uL.w + um1.x + up1.x) - C2*(uL.x + uR.x + um2.x + up2.x) - 5.0f*uL.z) * inv_dx2;
    lu.y = (C1*(uL.z + uR.x + um1.y + up1.y) - C2*(uL.y + uR.y + um2.y + up2.y) - 5.0f*uL.w) * inv_dx2;
    lu.z = (C1*(uL.w + uR.y + um1.z + up1.z) - C2*(uL.z + uR.z + um2.z + up2.z) - 5.0f*uR.x) * inv_dx2;
    lu.w = (C1*(uR.x + uR.z + um1.w + up1.w) - C2*(uL.w + uR.w + um2.w + up2.w) - 5.0f*uR.y) * inv_dx2;
    lv.x = (C1*(vL.y + vL.w + vm1.x + vp1.x) - C2*(vL.x + vR.x + vm2.x + vp2.x) - 5.0f*vL.z) * inv_dx2;
    lv.y = (C1*(vL.z + vR.x + vm1.y + vp1.y) - C2*(vL.y + vR.y + vm2.y + vp2.y) - 5.0f*vL.w) * inv_dx2;
    lv.z = (C1*(vL.w + vR.y + vm1.z + vp1.z) - C2*(vL.z + vR.z + vm2.z + vp2.z) - 5.0f*vR.x) * inv_dx2;
    lv.w = (C1*(vR.x + vR.z + vm1.w + vp1.w) - C2*(vL.w + vR.w + vm2.w + vp2.w) - 5.0f*vR.y) * inv_dx2;

    vf4 ucn = {uL.z, uL.w, uR.x, uR.y};   // centers at t
    vf4 vcn = {vL.z, vL.w, vR.x, vR.y};

    if (t == 0) { s.u_l0 = lu; s.v_l0 = lv; }

    if (t == 2 && act) {
        // emit t=0 one-sided: c0=cm1, c1=cc, c2=ucn, lap=l0
        vf4 fu, fv;
        GS_T0(x); GS_T0(y); GS_T0(z); GS_T0(w);
        __builtin_nontemporal_store(fu, (vf4*)(outu));
        __builtin_nontemporal_store(fv, (vf4*)(outv));
    }

    if (t >= 2 && act) {
        // emit t-1 interior: center=cc, u_t=(c_t - c_{t-2})/(2DT), lap=lm1
        vf4 fu, fv;
        GS_INT(x); GS_INT(y); GS_INT(z); GS_INT(w);
        __builtin_nontemporal_store(fu, (vf4*)(outu + (size_t)(t - 1) * T_OUT));
        __builtin_nontemporal_store(fv, (vf4*)(outv + (size_t)(t - 1) * T_OUT));
    }

    s.u_cm2 = s.u_cm1; s.u_cm1 = s.u_cc; s.u_cc = ucn; s.u_lm1 = lu;
    s.v_cm2 = s.v_cm1; s.v_cm1 = s.v_cc; s.v_cc = vcn; s.v_lm1 = lv;
}

static __device__ __forceinline__ void gs_tail(
    GSRow& s, bool act, float* __restrict__ outu, float* __restrict__ outv)
{
    const float inv_dt = 20.0f;
    const float Du = 0.16f, Dv = 0.08f, fR = 0.06f, kR = 0.062f;
    if (!act) return;
    // emit t=19 one-sided: c17=cm2, c18=cm1, c19=cc, lap19=lm1
    vf4 fu, fv;
    GS_TN(x); GS_TN(y); GS_TN(z); GS_TN(w);
    __builtin_nontemporal_store(fu, (vf4*)(outu + (size_t)19 * T_OUT));
    __builtin_nontemporal_store(fv, (vf4*)(outv + (size_t)19 * T_OUT));
}

__global__ __launch_bounds__(256, 1) void gs_loss_kernel(
    const float* __restrict__ in, float* __restrict__ out)
{
    // [buf][row][col]: rows 0..11 = u rows y0..y0+11, rows 12..23 = v. 48 KB.
    __shared__ float lds[2][24][256];

    const int tid = threadIdx.x;
    const int w   = tid >> 6;           // wave id (0..3)
    const int ln  = tid & 63;           // lane (0..63)

    const int b     = blockIdx.x & 7;   // batch -> XCD pinning
    const int ytile = blockIdx.x >> 3;  // 0..31
    const int y0    = ytile * 8;        // 0..248 (tile 31 ragged: 4 rows)

    const int planeStride = 256 * 256;
    const int bStride     = 3 * planeStride;
    const int tStride     = 24 * planeStride;

    const int col = ln * 4;             // staging column (16B aligned)
    const float* base0 = in + (size_t)b * bStride + planeStride;  // u, t=0

    // staging global rows (clamped to 255 for the ragged last tile; clamped
    // rows land in LDS rows 8..11 whose consumers are store-masked)
    const int gr0 = y0 + w;
    const int gr1 = (y0 + w + 4 < 256) ? (y0 + w + 4) : 255;
    const int gr2 = (y0 + w + 8 < 256) ? (y0 + w + 8) : 255;
    const size_t r0 = (size_t)gr0 * 256 + col;
    const size_t r1 = (size_t)gr1 * 256 + col;
    const size_t r2 = (size_t)gr2 * 256 + col;

    // compute role: thread owns rows y0+w and y0+w+4, cols x0..x0+3
    const int x0 = ln * 4;
    const bool active = (ln < 63);               // 252 of 256 x-positions
    const bool act2   = active && (y0 + w + 4 < 252);  // tile 31: row2 off

    const int total = 20 * T_OUT;
    float* outu1 = out + ((size_t)b * 252 + (y0 + w)) * 252 + x0;
    float* outv1 = outu1 + total;
    const int y2 = act2 ? (y0 + w + 4) : (y0 + w);     // keep ptr in-bounds
    float* outu2 = out + ((size_t)b * 252 + y2) * 252 + x0;
    float* outv2 = outu2 + total;

    GSRow s1{}, s2{};

    vf4 sA0, sA1, sA2, sA3, sA4, sA5;   // prefetch set A (even t)
    vf4 sB0, sB1, sB2, sB3, sB4, sB5;   // prefetch set B (odd t)

#define ISSUE_A(t) { const float* bt = base0 + (size_t)(t) * tStride; \
    sA0 = *(const vf4*)(bt + r0); \
    sA1 = *(const vf4*)(bt + r1); \
    sA2 = *(const vf4*)(bt + r2); \
    sA3 = *(const vf4*)(bt + planeStride + r0); \
    sA4 = *(const vf4*)(bt + planeStride + r1); \
    sA5 = *(const vf4*)(bt + planeStride + r2); }
#define ISSUE_B(t) { const float* bt = base0 + (size_t)(t) * tStride; \
    sB0 = *(const vf4*)(bt + r0); \
    sB1 = *(const vf4*)(bt + r1); \
    sB2 = *(const vf4*)(bt + r2); \
    sB3 = *(const vf4*)(bt + planeStride + r0); \
    sB4 = *(const vf4*)(bt + planeStride + r1); \
    sB5 = *(const vf4*)(bt + planeStride + r2); }

    ISSUE_A(0);
    ISSUE_B(1);

#pragma unroll
    for (int t = 0; t < 20; ++t) {
        float (*L)[256] = lds[t & 1];

        // stage t (compiler emits the partial vmcnt for this set's arrival)
        if ((t & 1) == 0) {
            *(vf4*)&L[w     ][col] = sA0;
            *(vf4*)&L[w + 4 ][col] = sA1;
            *(vf4*)&L[w + 8 ][col] = sA2;
            *(vf4*)&L[w + 12][col] = sA3;
            *(vf4*)&L[w + 16][col] = sA4;
            *(vf4*)&L[w + 20][col] = sA5;
        } else {
            *(vf4*)&L[w     ][col] = sB0;
            *(vf4*)&L[w + 4 ][col] = sB1;
            *(vf4*)&L[w + 8 ][col] = sB2;
            *(vf4*)&L[w + 12][col] = sB3;
            *(vf4*)&L[w + 16][col] = sB4;
            *(vf4*)&L[w + 20][col] = sB5;
        }

        __syncthreads();
        // One barrier per t is safe: a wave writing lds[(t+2)&1] has passed
        // barrier(t+1), which implies every wave finished compute(t).

        // prefetch t+2 into the register set just freed (2-iteration cover)
        if (t + 2 < 20) {
            if ((t & 1) == 0) { ISSUE_A(t + 2); } else { ISSUE_B(t + 2); }
        }

        gs_step(L, w,     x0, t, s1, active, outu1, outv1);
        gs_step(L, w + 4, x0, t, s2, act2,   outu2, outv2);
    }

    gs_tail(s1, active, outu1, outv1);
    gs_tail(s2, act2,   outu2, outv2);
}

extern "C" void kernel_launch(void* const* d_in, const int* in_sizes, int n_in,
                              void* d_out, int out_size, void* d_ws, size_t ws_size,
                              hipStream_t stream) {
    const float* in = (const float*)d_in[0];
    float* out = (float*)d_out;

    // 8 b * 32 y-tiles = 256 blocks of 256 threads (1 block/CU, 48KB LDS)
    gs_loss_kernel<<<8 * 32, 256, 0, stream>>>(in, out);
}